// Round 1
// baseline (679.917 us; speedup 1.0000x reference)
//
#include <hip/hip_runtime.h>

#define N_NODES 20000
#define N_EDGES 320000
#define DIM 512

// ---------------------------------------------------------------- small utils
__global__ void k_init_cnt(int* cnt) {
    int i = blockIdx.x * blockDim.x + threadIdx.x;
    if (i < N_NODES) cnt[i] = 0;
}

__global__ void k_count(const int* __restrict__ dst, int* __restrict__ cnt) {
    int e = blockIdx.x * blockDim.x + threadIdx.x;
    if (e < N_EDGES) atomicAdd(&cnt[dst[e]], 1);
}

// single-block exclusive scan over N_NODES counts -> offs[0..N]
__global__ void k_scan(const int* __restrict__ cnt, int* __restrict__ offs) {
    __shared__ int buf[1024];
    __shared__ int carry_s;
    int tid = threadIdx.x;
    if (tid == 0) { carry_s = 0; offs[0] = 0; }
    __syncthreads();
    for (int base = 0; base < N_NODES; base += 1024) {
        int v = (base + tid < N_NODES) ? cnt[base + tid] : 0;
        buf[tid] = v;
        __syncthreads();
        for (int off = 1; off < 1024; off <<= 1) {
            int t = (tid >= off) ? buf[tid - off] : 0;
            __syncthreads();
            buf[tid] += t;
            __syncthreads();
        }
        if (base + tid < N_NODES) offs[base + tid + 1] = carry_s + buf[tid];
        __syncthreads();
        if (tid == 0) carry_s += buf[1023];
        __syncthreads();
    }
}

__global__ void k_dinv_cursor(const int* __restrict__ cnt, const int* __restrict__ offs,
                              float* __restrict__ dinv, int* __restrict__ cursor) {
    int i = blockIdx.x * blockDim.x + threadIdx.x;
    if (i < N_NODES) {
        dinv[i] = rsqrtf((float)cnt[i] + 1.0f);  // +1 self-loop
        cursor[i] = offs[i];
    }
}

__global__ void k_fill(const int* __restrict__ src, const int* __restrict__ dst,
                       int* __restrict__ cursor, int* __restrict__ csr_src) {
    int e = blockIdx.x * blockDim.x + threadIdx.x;
    if (e < N_EDGES) {
        int d = dst[e];
        int pos = atomicAdd(&cursor[d], 1);
        csr_src[pos] = src[e];
    }
}

// ---------------------------------------------------------------- fp32 GEMM
// C[M,512] = A[M,512] @ B[512,512], 64x64 tile, 16x16 threads, 4x4 per thread
__global__ __launch_bounds__(256) void k_gemm(const float* __restrict__ A,
                                              const float* __restrict__ B,
                                              float* __restrict__ C, int M) {
    __shared__ float As[16][68];  // [k][m], stride 68 keeps 16B alignment
    __shared__ float Bs[16][68];  // [k][n]

    int tx = threadIdx.x, ty = threadIdx.y;
    int tid = ty * 16 + tx;
    int rowBase = blockIdx.x * 64;
    int colBase = blockIdx.y * 64;

    // A-load mapping: lm = row in tile, lk4 = starting k of a float4
    int lm  = tid >> 2;
    int lk4 = (tid & 3) * 4;
    // B-load mapping
    int bk = tid >> 4;         // 0..15
    int bc = (tid & 15) * 4;   // 0..60

    float acc[4][4];
#pragma unroll
    for (int i = 0; i < 4; ++i)
#pragma unroll
        for (int j = 0; j < 4; ++j) acc[i][j] = 0.f;

    for (int k0 = 0; k0 < DIM; k0 += 16) {
        int arow = rowBase + lm;
        float4 av = make_float4(0.f, 0.f, 0.f, 0.f);
        if (arow < M) av = *(const float4*)&A[(size_t)arow * DIM + k0 + lk4];
        As[lk4 + 0][lm] = av.x;
        As[lk4 + 1][lm] = av.y;
        As[lk4 + 2][lm] = av.z;
        As[lk4 + 3][lm] = av.w;

        float4 bv = *(const float4*)&B[(size_t)(k0 + bk) * DIM + colBase + bc];
        *(float4*)&Bs[bk][bc] = bv;
        __syncthreads();

#pragma unroll
        for (int kk = 0; kk < 16; ++kk) {
            float4 a = *(const float4*)&As[kk][ty * 4];
            float4 b = *(const float4*)&Bs[kk][tx * 4];
            float ar[4] = {a.x, a.y, a.z, a.w};
            float br[4] = {b.x, b.y, b.z, b.w};
#pragma unroll
            for (int i = 0; i < 4; ++i)
#pragma unroll
                for (int j = 0; j < 4; ++j) acc[i][j] = fmaf(ar[i], br[j], acc[i][j]);
        }
        __syncthreads();
    }

#pragma unroll
    for (int i = 0; i < 4; ++i) {
        int row = rowBase + ty * 4 + i;
        if (row < M) {
            float4 o = make_float4(acc[i][0], acc[i][1], acc[i][2], acc[i][3]);
            *(float4*)&C[(size_t)row * DIM + colBase + tx * 4] = o;
        }
    }
}

// ---------------------------------------------------------------- aggregation
// out[d] = relu( dinv_d * ( sum_e dinv_s * h[s]  +  dinv_d * h[d] ) + bias )
__global__ __launch_bounds__(256) void k_agg(const float* __restrict__ h,
                                             const float* __restrict__ dinv,
                                             const int* __restrict__ offs,
                                             const int* __restrict__ csr_src,
                                             const float* __restrict__ bias,
                                             float* __restrict__ out) {
    int d = blockIdx.x;
    int tid = threadIdx.x;
    float dd = dinv[d];
    int beg = offs[d], end = offs[d + 1];

    float acc0 = dd * h[(size_t)d * DIM + tid];
    float acc1 = dd * h[(size_t)d * DIM + tid + 256];
    for (int e = beg; e < end; ++e) {
        int s = csr_src[e];
        float w = dinv[s];
        acc0 += w * h[(size_t)s * DIM + tid];
        acc1 += w * h[(size_t)s * DIM + tid + 256];
    }
    out[(size_t)d * DIM + tid]       = fmaxf(fmaf(dd, acc0, bias[tid]), 0.f);
    out[(size_t)d * DIM + tid + 256] = fmaxf(fmaf(dd, acc1, bias[tid + 256]), 0.f);
}

// ---------------------------------------------------------------- max pool
__global__ void k_zero_out(float* out) {
    int f = blockIdx.x * blockDim.x + threadIdx.x;
    if (f < DIM) out[f] = 0.f;
}

// values are post-ReLU (>=0), so int-compare == float-compare
__global__ __launch_bounds__(256) void k_maxpool(const float* __restrict__ x,
                                                 float* __restrict__ out) {
    int f = blockIdx.x * blockDim.x + threadIdx.x;  // gridDim.x = 2
    int chunk = blockIdx.y;                          // gridDim.y = 64
    int i0 = chunk * 313;
    int i1 = min(i0 + 313, N_NODES);
    float m = 0.f;
    for (int i = i0; i < i1; ++i) m = fmaxf(m, x[(size_t)i * DIM + f]);
    atomicMax((int*)&out[f], __float_as_int(m));
}

// ---------------------------------------------------------------- launch
extern "C" void kernel_launch(void* const* d_in, const int* in_sizes, int n_in,
                              void* d_out, int out_size, void* d_ws, size_t ws_size,
                              hipStream_t stream) {
    const float* features = (const float*)d_in[0];
    const int*   ei       = (const int*)d_in[1];
    const float* W1       = (const float*)d_in[3];
    const float* b1       = (const float*)d_in[4];
    const float* W2       = (const float*)d_in[5];
    const float* b2       = (const float*)d_in[6];
    float* out = (float*)d_out;

    const int* src = ei;
    const int* dst = ei + N_EDGES;

    // workspace carve-up
    char* p = (char*)d_ws;
    auto alloc = [&](size_t bytes) { void* r = p; p += (bytes + 255) & ~(size_t)255; return r; };
    int*   cnt    = (int*)alloc(N_NODES * 4);
    int*   offs   = (int*)alloc((N_NODES + 1) * 4);
    int*   cursor = (int*)alloc(N_NODES * 4);
    float* dinv   = (float*)alloc(N_NODES * 4);
    int*   csr    = (int*)alloc(N_EDGES * 4);
    float* h      = (float*)alloc((size_t)N_NODES * DIM * 4);
    float* x1     = (float*)alloc((size_t)N_NODES * DIM * 4);

    // --- graph norm + CSR build
    k_init_cnt<<<(N_NODES + 255) / 256, 256, 0, stream>>>(cnt);
    k_count<<<(N_EDGES + 255) / 256, 256, 0, stream>>>(dst, cnt);
    k_scan<<<1, 1024, 0, stream>>>(cnt, offs);
    k_dinv_cursor<<<(N_NODES + 255) / 256, 256, 0, stream>>>(cnt, offs, dinv, cursor);
    k_fill<<<(N_EDGES + 255) / 256, 256, 0, stream>>>(src, dst, cursor, csr);

    dim3 gblk(16, 16);
    dim3 ggrd((N_NODES + 63) / 64, DIM / 64);

    // --- layer 1
    k_gemm<<<ggrd, gblk, 0, stream>>>(features, W1, h, N_NODES);
    k_agg<<<N_NODES, 256, 0, stream>>>(h, dinv, offs, csr, b1, x1);

    // --- layer 2
    k_gemm<<<ggrd, gblk, 0, stream>>>(x1, W2, h, N_NODES);
    k_agg<<<N_NODES, 256, 0, stream>>>(h, dinv, offs, csr, b2, x1);

    // --- global max pool
    k_zero_out<<<2, 256, 0, stream>>>(out);
    dim3 mgrd(2, 64);
    k_maxpool<<<mgrd, 256, 0, stream>>>(x1, out);
}

// Round 2
// 473.406 us; speedup vs baseline: 1.4362x; 1.4362x over previous
//
#include <hip/hip_runtime.h>

#define N_NODES 20000
#define MP      20096   // N_NODES padded to multiple of 128
#define N_EDGES 320000
#define DIM     512

typedef _Float16 half8 __attribute__((ext_vector_type(8)));
typedef _Float16 half4v __attribute__((ext_vector_type(4)));
typedef float floatx4 __attribute__((ext_vector_type(4)));

#define GLD16(g, l) __builtin_amdgcn_global_load_lds( \
    (const __attribute__((address_space(1))) unsigned int*)(g), \
    (__attribute__((address_space(3))) unsigned int*)(l), 16, 0, 0)

// ---------------------------------------------------------------- small utils
__global__ void k_init_cnt(int* cnt) {
    int i = blockIdx.x * blockDim.x + threadIdx.x;
    if (i < N_NODES) cnt[i] = 0;
}

__global__ void k_count(const int* __restrict__ dst, int* __restrict__ cnt) {
    int e = blockIdx.x * blockDim.x + threadIdx.x;
    if (e < N_EDGES) atomicAdd(&cnt[dst[e]], 1);
}

// single-block exclusive scan over N_NODES counts -> offs[0..N]
__global__ void k_scan(const int* __restrict__ cnt, int* __restrict__ offs) {
    __shared__ int buf[1024];
    __shared__ int carry_s;
    int tid = threadIdx.x;
    if (tid == 0) { carry_s = 0; offs[0] = 0; }
    __syncthreads();
    for (int base = 0; base < N_NODES; base += 1024) {
        int v = (base + tid < N_NODES) ? cnt[base + tid] : 0;
        buf[tid] = v;
        __syncthreads();
        for (int off = 1; off < 1024; off <<= 1) {
            int t = (tid >= off) ? buf[tid - off] : 0;
            __syncthreads();
            buf[tid] += t;
            __syncthreads();
        }
        if (base + tid < N_NODES) offs[base + tid + 1] = carry_s + buf[tid];
        __syncthreads();
        if (tid == 0) carry_s += buf[1023];
        __syncthreads();
    }
}

__global__ void k_dinv_cursor(const int* __restrict__ cnt, const int* __restrict__ offs,
                              float* __restrict__ dinv, int* __restrict__ cursor) {
    int i = blockIdx.x * blockDim.x + threadIdx.x;
    if (i < N_NODES) {
        dinv[i] = rsqrtf((float)cnt[i] + 1.0f);  // +1 self-loop
        cursor[i] = offs[i];
    }
}

__global__ void k_fill(const int* __restrict__ src, const int* __restrict__ dst,
                       int* __restrict__ cursor, int* __restrict__ csr_src) {
    int e = blockIdx.x * blockDim.x + threadIdx.x;
    if (e < N_EDGES) {
        int d = dst[e];
        int pos = atomicAdd(&cursor[d], 1);
        csr_src[pos] = src[e];
    }
}

// ---------------------------------------------------------------- converts
// features fp32 [N_NODES x 512] -> f16 [MP x 512], pad rows zero
__global__ __launch_bounds__(256) void k_cvt_feat(const float* __restrict__ F,
                                                  _Float16* __restrict__ A) {
    int i = blockIdx.x * blockDim.x + threadIdx.x;  // over MP*DIM/4
    int e = i * 4;
    int row = e >> 9;
    half4v o;
    if (row < N_NODES) {
        float4 v = *(const float4*)&F[e];
        o[0] = (_Float16)v.x; o[1] = (_Float16)v.y;
        o[2] = (_Float16)v.z; o[3] = (_Float16)v.w;
    } else {
        o[0] = o[1] = o[2] = o[3] = (_Float16)0.f;
    }
    *(half4v*)&A[e] = o;
}

// W fp32 [k][n] row-major -> Wt f16 [n][k] (transposed)
__global__ __launch_bounds__(256) void k_cvt_w(const float* __restrict__ W,
                                               _Float16* __restrict__ Wt) {
    __shared__ float tile[32][33];
    int bx = blockIdx.x * 32, by = blockIdx.y * 32;
    int x = threadIdx.x & 31, y4 = (threadIdx.x >> 5) * 4;
#pragma unroll
    for (int r = 0; r < 4; ++r)
        tile[y4 + r][x] = W[(size_t)(by + y4 + r) * DIM + bx + x];
    __syncthreads();
#pragma unroll
    for (int r = 0; r < 4; ++r)
        Wt[(size_t)(bx + y4 + r) * DIM + by + x] = (_Float16)tile[x][y4 + r];
}

// ---------------------------------------------------------------- MFMA GEMM
// C[MP,512] fp32 = A[MP,512] f16  @  Bt[n][k] f16 (B transposed)
// 128x128 tile, BK=32, 4 waves, each wave 64x64 = 4x4 of 16x16x32 MFMA
__global__ __launch_bounds__(256) void k_gemm_f16(const _Float16* __restrict__ A,
                                                  const _Float16* __restrict__ Bt,
                                                  float* __restrict__ C) {
    __shared__ _Float16 As[128 * 32];  // [m][k], k contiguous
    __shared__ _Float16 Bs[128 * 32];  // [n][k], k contiguous

    int t = threadIdx.x;
    int w = t >> 6, lane = t & 63;
    int lm = lane & 15, quad = lane >> 4;
    int m0 = blockIdx.x * 128, n0 = blockIdx.y * 128;
    int wm = (w & 1) * 64, wn = (w >> 1) * 64;

    floatx4 acc[4][4];
#pragma unroll
    for (int i = 0; i < 4; ++i)
#pragma unroll
        for (int j = 0; j < 4; ++j) acc[i][j] = (floatx4){0.f, 0.f, 0.f, 0.f};

    for (int k0 = 0; k0 < DIM; k0 += 32) {
        __syncthreads();  // prior-iteration LDS reads complete
#pragma unroll
        for (int i = 0; i < 2; ++i) {
            int s = i * 256 + t;          // segment id, 16B each; lane-contiguous per wave
            int m = s >> 2, kk = (s & 3) * 8;
            GLD16(A + (size_t)(m0 + m) * DIM + k0 + kk, As + s * 8);
            GLD16(Bt + (size_t)(n0 + m) * DIM + k0 + kk, Bs + s * 8);
        }
        __syncthreads();  // staging (vmcnt) drained

        half8 af[4], bf[4];
#pragma unroll
        for (int i = 0; i < 4; ++i)
            af[i] = *(const half8*)&As[(wm + i * 16 + lm) * 32 + quad * 8];
#pragma unroll
        for (int j = 0; j < 4; ++j)
            bf[j] = *(const half8*)&Bs[(wn + j * 16 + lm) * 32 + quad * 8];
#pragma unroll
        for (int i = 0; i < 4; ++i)
#pragma unroll
            for (int j = 0; j < 4; ++j)
                acc[i][j] = __builtin_amdgcn_mfma_f32_16x16x32_f16(af[i], bf[j], acc[i][j], 0, 0, 0);
    }

#pragma unroll
    for (int i = 0; i < 4; ++i)
#pragma unroll
        for (int j = 0; j < 4; ++j) {
            int col = n0 + wn + j * 16 + lm;
#pragma unroll
            for (int r = 0; r < 4; ++r) {
                int row = m0 + wm + i * 16 + quad * 4 + r;
                C[(size_t)row * DIM + col] = acc[i][j][r];
            }
        }
}

// ---------------------------------------------------------------- aggregation
// out[d] = relu( dinv_d * ( sum_e dinv_s * h[s]  +  dinv_d * h[d] ) + bias )
// f16-output version (grid = MP, zeros the pad rows)
__global__ __launch_bounds__(256) void k_agg_h(const float* __restrict__ h,
                                               const float* __restrict__ dinv,
                                               const int* __restrict__ offs,
                                               const int* __restrict__ csr_src,
                                               const float* __restrict__ bias,
                                               _Float16* __restrict__ out) {
    int d = blockIdx.x;
    int tid = threadIdx.x;
    if (d >= N_NODES) {
        out[(size_t)d * DIM + tid] = (_Float16)0.f;
        out[(size_t)d * DIM + tid + 256] = (_Float16)0.f;
        return;
    }
    float dd = dinv[d];
    int beg = offs[d], end = offs[d + 1];
    float acc0 = dd * h[(size_t)d * DIM + tid];
    float acc1 = dd * h[(size_t)d * DIM + tid + 256];
    for (int e = beg; e < end; ++e) {
        int s = csr_src[e];
        float ws = dinv[s];
        acc0 += ws * h[(size_t)s * DIM + tid];
        acc1 += ws * h[(size_t)s * DIM + tid + 256];
    }
    out[(size_t)d * DIM + tid] = (_Float16)fmaxf(fmaf(dd, acc0, bias[tid]), 0.f);
    out[(size_t)d * DIM + tid + 256] = (_Float16)fmaxf(fmaf(dd, acc1, bias[tid + 256]), 0.f);
}

// fp32-output version (grid = N_NODES)
__global__ __launch_bounds__(256) void k_agg_f(const float* __restrict__ h,
                                               const float* __restrict__ dinv,
                                               const int* __restrict__ offs,
                                               const int* __restrict__ csr_src,
                                               const float* __restrict__ bias,
                                               float* __restrict__ out) {
    int d = blockIdx.x;
    int tid = threadIdx.x;
    float dd = dinv[d];
    int beg = offs[d], end = offs[d + 1];
    float acc0 = dd * h[(size_t)d * DIM + tid];
    float acc1 = dd * h[(size_t)d * DIM + tid + 256];
    for (int e = beg; e < end; ++e) {
        int s = csr_src[e];
        float ws = dinv[s];
        acc0 += ws * h[(size_t)s * DIM + tid];
        acc1 += ws * h[(size_t)s * DIM + tid + 256];
    }
    out[(size_t)d * DIM + tid] = fmaxf(fmaf(dd, acc0, bias[tid]), 0.f);
    out[(size_t)d * DIM + tid + 256] = fmaxf(fmaf(dd, acc1, bias[tid + 256]), 0.f);
}

// ---------------------------------------------------------------- max pool
__global__ void k_zero_out(float* out) {
    int f = blockIdx.x * blockDim.x + threadIdx.x;
    if (f < DIM) out[f] = 0.f;
}

// values are post-ReLU (>=0), so int-compare == float-compare
__global__ __launch_bounds__(256) void k_maxpool(const float* __restrict__ x,
                                                 float* __restrict__ out) {
    int f = blockIdx.x * blockDim.x + threadIdx.x;  // gridDim.x = 2
    int chunk = blockIdx.y;                          // gridDim.y = 64
    int i0 = chunk * 313;
    int i1 = min(i0 + 313, N_NODES);
    float m = 0.f;
    for (int i = i0; i < i1; ++i) m = fmaxf(m, x[(size_t)i * DIM + f]);
    atomicMax((int*)&out[f], __float_as_int(m));
}

// ---------------------------------------------------------------- launch
extern "C" void kernel_launch(void* const* d_in, const int* in_sizes, int n_in,
                              void* d_out, int out_size, void* d_ws, size_t ws_size,
                              hipStream_t stream) {
    const float* features = (const float*)d_in[0];
    const int*   ei       = (const int*)d_in[1];
    const float* W1       = (const float*)d_in[3];
    const float* b1       = (const float*)d_in[4];
    const float* W2       = (const float*)d_in[5];
    const float* b2       = (const float*)d_in[6];
    float* out = (float*)d_out;

    const int* src = ei;
    const int* dst = ei + N_EDGES;

    // workspace carve-up (x2 aliases the dead fA/Wt1/x1f region)
    char* p = (char*)d_ws;
    auto alloc = [&](size_t bytes) { void* r = p; p += (bytes + 255) & ~(size_t)255; return r; };
    int*      cnt    = (int*)alloc(N_NODES * 4);
    int*      offs   = (int*)alloc((N_NODES + 1) * 4);
    int*      cursor = (int*)alloc(N_NODES * 4);
    float*    dinv   = (float*)alloc(N_NODES * 4);
    int*      csr    = (int*)alloc(N_EDGES * 4);
    char*     aliasBase = p;
    _Float16* fA  = (_Float16*)alloc((size_t)MP * DIM * 2);   // 20.6 MB, dead after GEMM1
    _Float16* Wt1 = (_Float16*)alloc((size_t)DIM * DIM * 2);  // dead after GEMM1
    _Float16* x1f = (_Float16*)alloc((size_t)MP * DIM * 2);   // dead after GEMM2
    _Float16* Wt2 = (_Float16*)alloc((size_t)DIM * DIM * 2);
    float*    h   = (float*)alloc((size_t)MP * DIM * 4);      // 41.2 MB
    float*    x2  = (float*)aliasBase;  // 41.2 MB over fA+Wt1+x1f (41.7 MB) -- safe: all dead

    // --- graph norm + CSR build
    k_init_cnt<<<(N_NODES + 255) / 256, 256, 0, stream>>>(cnt);
    k_count<<<(N_EDGES + 255) / 256, 256, 0, stream>>>(dst, cnt);
    k_scan<<<1, 1024, 0, stream>>>(cnt, offs);
    k_dinv_cursor<<<(N_NODES + 255) / 256, 256, 0, stream>>>(cnt, offs, dinv, cursor);
    k_fill<<<(N_EDGES + 255) / 256, 256, 0, stream>>>(src, dst, cursor, csr);

    // --- convert inputs to f16 (A padded, W transposed)
    k_cvt_feat<<<(MP * DIM / 4 + 255) / 256, 256, 0, stream>>>(features, fA);
    dim3 wgrd(16, 16);
    k_cvt_w<<<wgrd, 256, 0, stream>>>(W1, Wt1);
    k_cvt_w<<<wgrd, 256, 0, stream>>>(W2, Wt2);

    dim3 ggrd(MP / 128, DIM / 128);

    // --- layer 1
    k_gemm_f16<<<ggrd, 256, 0, stream>>>(fA, Wt1, h);
    k_agg_h<<<MP, 256, 0, stream>>>(h, dinv, offs, csr, b1, x1f);

    // --- layer 2
    k_gemm_f16<<<ggrd, 256, 0, stream>>>(x1f, Wt2, h);
    k_agg_f<<<N_NODES, 256, 0, stream>>>(h, dinv, offs, csr, b2, x2);

    // --- global max pool
    k_zero_out<<<2, 256, 0, stream>>>(out);
    dim3 mgrd(2, 64);
    k_maxpool<<<mgrd, 256, 0, stream>>>(x2, out);
}

// Round 3
// 371.068 us; speedup vs baseline: 1.8323x; 1.2758x over previous
//
#include <hip/hip_runtime.h>

#define N_NODES 20000
#define MP      20096   // N_NODES padded to multiple of 128
#define N_EDGES 320000
#define DIM     512

typedef _Float16 half8 __attribute__((ext_vector_type(8)));
typedef _Float16 half4v __attribute__((ext_vector_type(4)));
typedef float floatx4 __attribute__((ext_vector_type(4)));

#define GLD16(g, l) __builtin_amdgcn_global_load_lds( \
    (const __attribute__((address_space(1))) unsigned int*)(g), \
    (__attribute__((address_space(3))) unsigned int*)(l), 16, 0, 0)

// ---------------------------------------------------------------- small utils
__global__ void k_init_cnt(int* cnt) {
    int i = blockIdx.x * blockDim.x + threadIdx.x;
    if (i < N_NODES) cnt[i] = 0;
}

__global__ void k_count(const int* __restrict__ dst, int* __restrict__ cnt) {
    int e = blockIdx.x * blockDim.x + threadIdx.x;
    if (e < N_EDGES) atomicAdd(&cnt[dst[e]], 1);
}

// single-block exclusive scan over N_NODES counts -> offs[0..N]
__global__ void k_scan(const int* __restrict__ cnt, int* __restrict__ offs) {
    __shared__ int buf[1024];
    __shared__ int carry_s;
    int tid = threadIdx.x;
    if (tid == 0) { carry_s = 0; offs[0] = 0; }
    __syncthreads();
    for (int base = 0; base < N_NODES; base += 1024) {
        int v = (base + tid < N_NODES) ? cnt[base + tid] : 0;
        buf[tid] = v;
        __syncthreads();
        for (int off = 1; off < 1024; off <<= 1) {
            int t = (tid >= off) ? buf[tid - off] : 0;
            __syncthreads();
            buf[tid] += t;
            __syncthreads();
        }
        if (base + tid < N_NODES) offs[base + tid + 1] = carry_s + buf[tid];
        __syncthreads();
        if (tid == 0) carry_s += buf[1023];
        __syncthreads();
    }
}

// dinv sized MP: zeros on pad rows (also poison-proofs GEMM epilogue)
__global__ void k_dinv_cursor(const int* __restrict__ cnt, const int* __restrict__ offs,
                              float* __restrict__ dinv, int* __restrict__ cursor) {
    int i = blockIdx.x * blockDim.x + threadIdx.x;
    if (i < N_NODES) {
        dinv[i] = rsqrtf((float)cnt[i] + 1.0f);  // +1 self-loop
        cursor[i] = offs[i];
    } else if (i < MP) {
        dinv[i] = 0.f;
    }
}

__global__ void k_fill(const int* __restrict__ src, const int* __restrict__ dst,
                       int* __restrict__ cursor, int* __restrict__ csr_src) {
    int e = blockIdx.x * blockDim.x + threadIdx.x;
    if (e < N_EDGES) {
        int d = dst[e];
        int pos = atomicAdd(&cursor[d], 1);
        csr_src[pos] = src[e];
    }
}

// ---------------------------------------------------------------- converts
// features fp32 [N_NODES x 512] -> f16 [MP x 512], pad rows zero
__global__ __launch_bounds__(256) void k_cvt_feat(const float* __restrict__ F,
                                                  _Float16* __restrict__ A) {
    int i = blockIdx.x * blockDim.x + threadIdx.x;  // over MP*DIM/4
    int e = i * 4;
    int row = e >> 9;
    half4v o;
    if (row < N_NODES) {
        float4 v = *(const float4*)&F[e];
        o[0] = (_Float16)v.x; o[1] = (_Float16)v.y;
        o[2] = (_Float16)v.z; o[3] = (_Float16)v.w;
    } else {
        o[0] = o[1] = o[2] = o[3] = (_Float16)0.f;
    }
    *(half4v*)&A[e] = o;
}

// W fp32 [k][n] row-major -> Wt f16 [n][k] (transposed)
__global__ __launch_bounds__(256) void k_cvt_w(const float* __restrict__ W,
                                               _Float16* __restrict__ Wt) {
    __shared__ float tile[32][33];
    int bx = blockIdx.x * 32, by = blockIdx.y * 32;
    int x = threadIdx.x & 31, y4 = (threadIdx.x >> 5) * 4;
#pragma unroll
    for (int r = 0; r < 4; ++r)
        tile[y4 + r][x] = W[(size_t)(by + y4 + r) * DIM + bx + x];
    __syncthreads();
#pragma unroll
    for (int r = 0; r < 4; ++r)
        Wt[(size_t)(bx + y4 + r) * DIM + by + x] = (_Float16)tile[x][y4 + r];
}

// ---------------------------------------------------------------- MFMA GEMM
// g[MP,512] f16 = dinv[row] * (A[MP,512] f16 @ Bt[n][k] f16)
// 128x128 tile, BK=32, 4 waves, each wave 64x64 = 4x4 of 16x16x32 MFMA
__global__ __launch_bounds__(256) void k_gemm_f16(const _Float16* __restrict__ A,
                                                  const _Float16* __restrict__ Bt,
                                                  const float* __restrict__ dinv,
                                                  _Float16* __restrict__ G) {
    __shared__ _Float16 As[128 * 32];  // [m][k], k contiguous
    __shared__ _Float16 Bs[128 * 32];  // [n][k], k contiguous

    int t = threadIdx.x;
    int w = t >> 6, lane = t & 63;
    int lm = lane & 15, quad = lane >> 4;
    int m0 = blockIdx.x * 128, n0 = blockIdx.y * 128;
    int wm = (w & 1) * 64, wn = (w >> 1) * 64;

    floatx4 acc[4][4];
#pragma unroll
    for (int i = 0; i < 4; ++i)
#pragma unroll
        for (int j = 0; j < 4; ++j) acc[i][j] = (floatx4){0.f, 0.f, 0.f, 0.f};

    for (int k0 = 0; k0 < DIM; k0 += 32) {
        __syncthreads();  // prior-iteration LDS reads complete
#pragma unroll
        for (int i = 0; i < 2; ++i) {
            int s = i * 256 + t;          // segment id, 16B each; lane-contiguous per wave
            int m = s >> 2, kk = (s & 3) * 8;
            GLD16(A + (size_t)(m0 + m) * DIM + k0 + kk, As + s * 8);
            GLD16(Bt + (size_t)(n0 + m) * DIM + k0 + kk, Bs + s * 8);
        }
        __syncthreads();  // staging (vmcnt) drained

        half8 af[4], bf[4];
#pragma unroll
        for (int i = 0; i < 4; ++i)
            af[i] = *(const half8*)&As[(wm + i * 16 + lm) * 32 + quad * 8];
#pragma unroll
        for (int j = 0; j < 4; ++j)
            bf[j] = *(const half8*)&Bs[(wn + j * 16 + lm) * 32 + quad * 8];
#pragma unroll
        for (int i = 0; i < 4; ++i)
#pragma unroll
            for (int j = 0; j < 4; ++j)
                acc[i][j] = __builtin_amdgcn_mfma_f32_16x16x32_f16(af[i], bf[j], acc[i][j], 0, 0, 0);
    }

#pragma unroll
    for (int i = 0; i < 4; ++i)
#pragma unroll
        for (int r = 0; r < 4; ++r) {
            int row = m0 + wm + i * 16 + quad * 4 + r;
            float dd = dinv[row];  // 0 on pad rows
#pragma unroll
            for (int j = 0; j < 4; ++j) {
                int col = n0 + wn + j * 16 + lm;
                G[(size_t)row * DIM + col] = (_Float16)(dd * acc[i][j][r]);
            }
        }
}

// ---------------------------------------------------------------- aggregation
// g[s] = dinv_s * h[s] (f16). out[d] = relu( dinv_d * (g[d] + sum_e g[s]) + bias )
// One wave per node; lane covers 8 contiguous features (16 B). f16 output.
// Grid covers nblocks*4 nodes; pad nodes (>= N_NODES) write zeros.
__global__ __launch_bounds__(256) void k_agg(const _Float16* __restrict__ g,
                                             const float* __restrict__ dinv,
                                             const int* __restrict__ offs,
                                             const int* __restrict__ csr_src,
                                             const float* __restrict__ bias,
                                             _Float16* __restrict__ out, int nNodesOut) {
    int node = blockIdx.x * 4 + (threadIdx.x >> 6);
    int lane = threadIdx.x & 63;
    int f0 = lane * 8;
    if (node >= nNodesOut) return;
    if (node >= N_NODES) {  // pad row: zero (x1f feeds GEMM2's A)
        half8 z;
#pragma unroll
        for (int i = 0; i < 8; ++i) z[i] = (_Float16)0.f;
        *(half8*)&out[(size_t)node * DIM + f0] = z;
        return;
    }
    float acc[8];
    half8 self = *(const half8*)&g[(size_t)node * DIM + f0];
#pragma unroll
    for (int i = 0; i < 8; ++i) acc[i] = (float)self[i];

    int beg = offs[node], end = offs[node + 1];
    for (int e = beg; e < end; ++e) {
        int s = csr_src[e];
        half8 v = *(const half8*)&g[(size_t)s * DIM + f0];
#pragma unroll
        for (int i = 0; i < 8; ++i) acc[i] += (float)v[i];
    }
    float dd = dinv[node];
    float4 b0 = *(const float4*)&bias[f0];
    float4 b1 = *(const float4*)&bias[f0 + 4];
    float bb[8] = {b0.x, b0.y, b0.z, b0.w, b1.x, b1.y, b1.z, b1.w};
    half8 o;
#pragma unroll
    for (int i = 0; i < 8; ++i) o[i] = (_Float16)fmaxf(fmaf(dd, acc[i], bb[i]), 0.f);
    *(half8*)&out[(size_t)node * DIM + f0] = o;
}

// ---------------------------------------------------------------- max pool
__global__ void k_zero_out(float* out) {
    int f = blockIdx.x * blockDim.x + threadIdx.x;
    if (f < DIM) out[f] = 0.f;
}

// values are post-ReLU (>=0), so int-compare == float-compare
__global__ __launch_bounds__(256) void k_maxpool(const _Float16* __restrict__ x,
                                                 float* __restrict__ out) {
    int f = blockIdx.x * blockDim.x + threadIdx.x;  // gridDim.x = 2
    int chunk = blockIdx.y;                          // gridDim.y = 64
    int i0 = chunk * 313;
    int i1 = min(i0 + 313, N_NODES);
    float m = 0.f;
    for (int i = i0; i < i1; ++i) m = fmaxf(m, (float)x[(size_t)i * DIM + f]);
    atomicMax((int*)&out[f], __float_as_int(m));
}

// ---------------------------------------------------------------- launch
extern "C" void kernel_launch(void* const* d_in, const int* in_sizes, int n_in,
                              void* d_out, int out_size, void* d_ws, size_t ws_size,
                              hipStream_t stream) {
    const float* features = (const float*)d_in[0];
    const int*   ei       = (const int*)d_in[1];
    const float* W1       = (const float*)d_in[3];
    const float* b1       = (const float*)d_in[4];
    const float* W2       = (const float*)d_in[5];
    const float* b2       = (const float*)d_in[6];
    float* out = (float*)d_out;

    const int* src = ei;
    const int* dst = ei + N_EDGES;

    // workspace carve-up
    char* p = (char*)d_ws;
    auto alloc = [&](size_t bytes) { void* r = p; p += (bytes + 255) & ~(size_t)255; return r; };
    int*      cnt    = (int*)alloc(N_NODES * 4);
    int*      offs   = (int*)alloc((N_NODES + 1) * 4);
    int*      cursor = (int*)alloc(N_NODES * 4);
    float*    dinv   = (float*)alloc(MP * 4);
    int*      csr    = (int*)alloc(N_EDGES * 4);
    _Float16* fA  = (_Float16*)alloc((size_t)MP * DIM * 2);   // GEMM1 A
    _Float16* Wt1 = (_Float16*)alloc((size_t)DIM * DIM * 2);
    _Float16* Wt2 = (_Float16*)alloc((size_t)DIM * DIM * 2);
    _Float16* gbuf = (_Float16*)alloc((size_t)MP * DIM * 2);  // g = dinv*h (f16)
    _Float16* x1f  = (_Float16*)alloc((size_t)MP * DIM * 2);  // layer-1 out / GEMM2 A
    _Float16* x2h  = (_Float16*)alloc((size_t)MP * DIM * 2);  // layer-2 out

    // --- graph norm + CSR build
    k_init_cnt<<<(N_NODES + 255) / 256, 256, 0, stream>>>(cnt);
    k_count<<<(N_EDGES + 255) / 256, 256, 0, stream>>>(dst, cnt);
    k_scan<<<1, 1024, 0, stream>>>(cnt, offs);
    k_dinv_cursor<<<(MP + 255) / 256, 256, 0, stream>>>(cnt, offs, dinv, cursor);
    k_fill<<<(N_EDGES + 255) / 256, 256, 0, stream>>>(src, dst, cursor, csr);

    // --- convert inputs to f16 (A padded, W transposed)
    k_cvt_feat<<<(MP * DIM / 4 + 255) / 256, 256, 0, stream>>>(features, fA);
    dim3 wgrd(16, 16);
    k_cvt_w<<<wgrd, 256, 0, stream>>>(W1, Wt1);
    k_cvt_w<<<wgrd, 256, 0, stream>>>(W2, Wt2);

    dim3 ggrd(MP / 128, DIM / 128);

    // --- layer 1
    k_gemm_f16<<<ggrd, 256, 0, stream>>>(fA, Wt1, dinv, gbuf);
    k_agg<<<MP / 4, 256, 0, stream>>>(gbuf, dinv, offs, csr, b1, x1f, MP);

    // --- layer 2
    k_gemm_f16<<<ggrd, 256, 0, stream>>>(x1f, Wt2, dinv, gbuf);
    k_agg<<<MP / 4, 256, 0, stream>>>(gbuf, dinv, offs, csr, b2, x2h, N_NODES);

    // --- global max pool
    k_zero_out<<<2, 256, 0, stream>>>(out);
    dim3 mgrd(2, 64);
    k_maxpool<<<mgrd, 256, 0, stream>>>(x2h, out);
}

// Round 4
// 319.990 us; speedup vs baseline: 2.1248x; 1.1596x over previous
//
#include <hip/hip_runtime.h>

#define N_NODES 20000
#define MP      20096   // N_NODES padded to multiple of 128
#define N_EDGES 320000
#define DIM     512
#define SCAN_BLOCKS 79  // ceil(20224/256), 79*256 = 20224 >= MP

typedef _Float16 half8 __attribute__((ext_vector_type(8)));
typedef _Float16 half4v __attribute__((ext_vector_type(4)));
typedef float floatx4 __attribute__((ext_vector_type(4)));

#define GLD16(g, l) __builtin_amdgcn_global_load_lds( \
    (const __attribute__((address_space(1))) unsigned int*)(g), \
    (__attribute__((address_space(3))) unsigned int*)(l), 16, 0, 0)

// ---------------------------------------------------------------- init
// zero cnt[N_NODES] and out[DIM] in one dispatch (grid SCAN_BLOCKS x 256)
__global__ void k_init(int* __restrict__ cnt, float* __restrict__ out) {
    int i = blockIdx.x * blockDim.x + threadIdx.x;
    if (i < N_NODES) cnt[i] = 0;
    if (i < DIM) out[i] = 0.f;
}

__global__ void k_count(const int* __restrict__ dst, int* __restrict__ cnt) {
    int e = blockIdx.x * blockDim.x + threadIdx.x;
    if (e < N_EDGES) atomicAdd(&cnt[dst[e]], 1);
}

// ---------------------------------------------------------------- parallel scan
// phase A: per-block sum of 256 counts
__global__ __launch_bounds__(256) void k_scan_a(const int* __restrict__ cnt,
                                                int* __restrict__ bsum) {
    __shared__ int buf[256];
    int gi = blockIdx.x * 256 + threadIdx.x;
    buf[threadIdx.x] = (gi < N_NODES) ? cnt[gi] : 0;
    __syncthreads();
    for (int off = 128; off > 0; off >>= 1) {
        if (threadIdx.x < off) buf[threadIdx.x] += buf[threadIdx.x + off];
        __syncthreads();
    }
    if (threadIdx.x == 0) bsum[blockIdx.x] = buf[0];
}

// phase B: exclusive scan of SCAN_BLOCKS partials, single small block
__global__ __launch_bounds__(128) void k_scan_b(const int* __restrict__ bsum,
                                                int* __restrict__ bbase) {
    __shared__ int buf[128];
    int tid = threadIdx.x;
    int v = (tid < SCAN_BLOCKS) ? bsum[tid] : 0;
    buf[tid] = v;
    __syncthreads();
    for (int off = 1; off < 128; off <<= 1) {
        int t = (tid >= off) ? buf[tid - off] : 0;
        __syncthreads();
        buf[tid] += t;
        __syncthreads();
    }
    if (tid < SCAN_BLOCKS) bbase[tid] = buf[tid] - v;  // exclusive
}

// phase C: in-block inclusive scan + base -> offs, cursor, dinv (dinv padded to MP)
__global__ __launch_bounds__(256) void k_scan_c(const int* __restrict__ cnt,
                                                const int* __restrict__ bbase,
                                                int* __restrict__ offs,
                                                int* __restrict__ cursor,
                                                float* __restrict__ dinv) {
    __shared__ int buf[256];
    int tid = threadIdx.x;
    int gi = blockIdx.x * 256 + tid;
    int v = (gi < N_NODES) ? cnt[gi] : 0;
    buf[tid] = v;
    __syncthreads();
    for (int off = 1; off < 256; off <<= 1) {
        int t = (tid >= off) ? buf[tid - off] : 0;
        __syncthreads();
        buf[tid] += t;
        __syncthreads();
    }
    int base = bbase[blockIdx.x];
    if (gi < N_NODES) {
        int incl = base + buf[tid];
        offs[gi + 1] = incl;
        cursor[gi] = incl - v;
        dinv[gi] = rsqrtf((float)v + 1.0f);  // +1 self-loop
        if (gi == 0) offs[0] = 0;
    } else if (gi < MP) {
        dinv[gi] = 0.f;  // pad rows: zero (poison-proofs GEMM epilogue)
    }
}

__global__ void k_fill(const int* __restrict__ src, const int* __restrict__ dst,
                       int* __restrict__ cursor, int* __restrict__ csr_src) {
    int e = blockIdx.x * blockDim.x + threadIdx.x;
    if (e < N_EDGES) {
        int d = dst[e];
        int pos = atomicAdd(&cursor[d], 1);
        csr_src[pos] = src[e];
    }
}

// ---------------------------------------------------------------- converts
// features fp32 [N_NODES x 512] -> f16 [MP x 512], pad rows zero
__global__ __launch_bounds__(256) void k_cvt_feat(const float* __restrict__ F,
                                                  _Float16* __restrict__ A) {
    int i = blockIdx.x * blockDim.x + threadIdx.x;  // over MP*DIM/4
    int e = i * 4;
    int row = e >> 9;
    half4v o;
    if (row < N_NODES) {
        float4 v = *(const float4*)&F[e];
        o[0] = (_Float16)v.x; o[1] = (_Float16)v.y;
        o[2] = (_Float16)v.z; o[3] = (_Float16)v.w;
    } else {
        o[0] = o[1] = o[2] = o[3] = (_Float16)0.f;
    }
    *(half4v*)&A[e] = o;
}

// W fp32 [k][n] row-major -> Wt f16 [n][k] (transposed); blockIdx.z picks W1/W2
__global__ __launch_bounds__(256) void k_cvt_w(const float* __restrict__ W1,
                                               const float* __restrict__ W2,
                                               _Float16* __restrict__ Wt1,
                                               _Float16* __restrict__ Wt2) {
    const float* W = blockIdx.z ? W2 : W1;
    _Float16* Wt = blockIdx.z ? Wt2 : Wt1;
    __shared__ float tile[32][33];
    int bx = blockIdx.x * 32, by = blockIdx.y * 32;
    int x = threadIdx.x & 31, y4 = (threadIdx.x >> 5) * 4;
#pragma unroll
    for (int r = 0; r < 4; ++r)
        tile[y4 + r][x] = W[(size_t)(by + y4 + r) * DIM + bx + x];
    __syncthreads();
#pragma unroll
    for (int r = 0; r < 4; ++r)
        Wt[(size_t)(bx + y4 + r) * DIM + by + x] = (_Float16)tile[x][y4 + r];
}

// ---------------------------------------------------------------- MFMA GEMM
// g[MP,512] f16 = dinv[row] * (A[MP,512] f16 @ Bt[n][k] f16)
// 128x128 tile, BK=32, 4 waves, each wave 64x64 = 4x4 of 16x16x32 MFMA
__global__ __launch_bounds__(256) void k_gemm_f16(const _Float16* __restrict__ A,
                                                  const _Float16* __restrict__ Bt,
                                                  const float* __restrict__ dinv,
                                                  _Float16* __restrict__ G) {
    __shared__ _Float16 As[128 * 32];  // [m][k], k contiguous
    __shared__ _Float16 Bs[128 * 32];  // [n][k], k contiguous

    int t = threadIdx.x;
    int w = t >> 6, lane = t & 63;
    int lm = lane & 15, quad = lane >> 4;
    int m0 = blockIdx.x * 128, n0 = blockIdx.y * 128;
    int wm = (w & 1) * 64, wn = (w >> 1) * 64;

    floatx4 acc[4][4];
#pragma unroll
    for (int i = 0; i < 4; ++i)
#pragma unroll
        for (int j = 0; j < 4; ++j) acc[i][j] = (floatx4){0.f, 0.f, 0.f, 0.f};

    for (int k0 = 0; k0 < DIM; k0 += 32) {
        __syncthreads();  // prior-iteration LDS reads complete
#pragma unroll
        for (int i = 0; i < 2; ++i) {
            int s = i * 256 + t;          // segment id, 16B each; lane-contiguous per wave
            int m = s >> 2, kk = (s & 3) * 8;
            GLD16(A + (size_t)(m0 + m) * DIM + k0 + kk, As + s * 8);
            GLD16(Bt + (size_t)(n0 + m) * DIM + k0 + kk, Bs + s * 8);
        }
        __syncthreads();  // staging (vmcnt) drained

        half8 af[4], bf[4];
#pragma unroll
        for (int i = 0; i < 4; ++i)
            af[i] = *(const half8*)&As[(wm + i * 16 + lm) * 32 + quad * 8];
#pragma unroll
        for (int j = 0; j < 4; ++j)
            bf[j] = *(const half8*)&Bs[(wn + j * 16 + lm) * 32 + quad * 8];
#pragma unroll
        for (int i = 0; i < 4; ++i)
#pragma unroll
            for (int j = 0; j < 4; ++j)
                acc[i][j] = __builtin_amdgcn_mfma_f32_16x16x32_f16(af[i], bf[j], acc[i][j], 0, 0, 0);
    }

#pragma unroll
    for (int i = 0; i < 4; ++i)
#pragma unroll
        for (int r = 0; r < 4; ++r) {
            int row = m0 + wm + i * 16 + quad * 4 + r;
            float dd = dinv[row];  // 0 on pad rows
#pragma unroll
            for (int j = 0; j < 4; ++j) {
                int col = n0 + wn + j * 16 + lm;
                G[(size_t)row * DIM + col] = (_Float16)(dd * acc[i][j][r]);
            }
        }
}

// ---------------------------------------------------------------- aggregation
// g[s] = dinv_s * h[s] (f16). out[d] = relu( dinv_d * (g[d] + sum_e g[s]) + bias )
// One wave per node; lane covers 8 contiguous features (16 B).
// Edge loop unrolled x4 with batched index loads -> 4 outstanding 1KB gathers.
__global__ __launch_bounds__(256) void k_agg(const _Float16* __restrict__ g,
                                             const float* __restrict__ dinv,
                                             const int* __restrict__ offs,
                                             const int* __restrict__ csr_src,
                                             const float* __restrict__ bias,
                                             _Float16* __restrict__ out, int nNodesOut) {
    int node = blockIdx.x * 4 + (threadIdx.x >> 6);
    int lane = threadIdx.x & 63;
    int f0 = lane * 8;
    if (node >= nNodesOut) return;
    if (node >= N_NODES) {  // pad row: zero (x1f feeds GEMM2's A)
        half8 z;
#pragma unroll
        for (int i = 0; i < 8; ++i) z[i] = (_Float16)0.f;
        *(half8*)&out[(size_t)node * DIM + f0] = z;
        return;
    }
    float acc[8];
    half8 self = *(const half8*)&g[(size_t)node * DIM + f0];
#pragma unroll
    for (int i = 0; i < 8; ++i) acc[i] = (float)self[i];

    int beg = offs[node], end = offs[node + 1];
    int e = beg;
    for (; e + 4 <= end; e += 4) {
        int s0 = csr_src[e], s1 = csr_src[e + 1], s2 = csr_src[e + 2], s3 = csr_src[e + 3];
        half8 v0 = *(const half8*)&g[(size_t)s0 * DIM + f0];
        half8 v1 = *(const half8*)&g[(size_t)s1 * DIM + f0];
        half8 v2 = *(const half8*)&g[(size_t)s2 * DIM + f0];
        half8 v3 = *(const half8*)&g[(size_t)s3 * DIM + f0];
#pragma unroll
        for (int i = 0; i < 8; ++i)
            acc[i] += (float)v0[i] + (float)v1[i] + (float)v2[i] + (float)v3[i];
    }
    for (; e < end; ++e) {
        int s = csr_src[e];
        half8 v = *(const half8*)&g[(size_t)s * DIM + f0];
#pragma unroll
        for (int i = 0; i < 8; ++i) acc[i] += (float)v[i];
    }
    float dd = dinv[node];
    float4 b0 = *(const float4*)&bias[f0];
    float4 b1 = *(const float4*)&bias[f0 + 4];
    float bb[8] = {b0.x, b0.y, b0.z, b0.w, b1.x, b1.y, b1.z, b1.w};
    half8 o;
#pragma unroll
    for (int i = 0; i < 8; ++i) o[i] = (_Float16)fmaxf(fmaf(dd, acc[i], bb[i]), 0.f);
    *(half8*)&out[(size_t)node * DIM + f0] = o;
}

// ---------------------------------------------------------------- max pool
// values are post-ReLU (>=0), so int-compare == float-compare; out pre-zeroed in k_init
__global__ __launch_bounds__(256) void k_maxpool(const _Float16* __restrict__ x,
                                                 float* __restrict__ out) {
    int f = blockIdx.x * blockDim.x + threadIdx.x;  // gridDim.x = 2
    int chunk = blockIdx.y;                          // gridDim.y = 64
    int i0 = chunk * 313;
    int i1 = min(i0 + 313, N_NODES);
    float m = 0.f;
    for (int i = i0; i < i1; ++i) m = fmaxf(m, (float)x[(size_t)i * DIM + f]);
    atomicMax((int*)&out[f], __float_as_int(m));
}

// ---------------------------------------------------------------- launch
extern "C" void kernel_launch(void* const* d_in, const int* in_sizes, int n_in,
                              void* d_out, int out_size, void* d_ws, size_t ws_size,
                              hipStream_t stream) {
    const float* features = (const float*)d_in[0];
    const int*   ei       = (const int*)d_in[1];
    const float* W1       = (const float*)d_in[3];
    const float* b1       = (const float*)d_in[4];
    const float* W2       = (const float*)d_in[5];
    const float* b2       = (const float*)d_in[6];
    float* out = (float*)d_out;

    const int* src = ei;
    const int* dst = ei + N_EDGES;

    // workspace carve-up
    char* p = (char*)d_ws;
    auto alloc = [&](size_t bytes) { void* r = p; p += (bytes + 255) & ~(size_t)255; return r; };
    int*      cnt    = (int*)alloc(N_NODES * 4);
    int*      offs   = (int*)alloc((N_NODES + 1) * 4);
    int*      cursor = (int*)alloc(N_NODES * 4);
    float*    dinv   = (float*)alloc(MP * 4);
    int*      csr    = (int*)alloc(N_EDGES * 4);
    int*      bsum   = (int*)alloc(SCAN_BLOCKS * 4);
    int*      bbase  = (int*)alloc(SCAN_BLOCKS * 4);
    _Float16* fA  = (_Float16*)alloc((size_t)MP * DIM * 2);   // GEMM1 A
    _Float16* Wt1 = (_Float16*)alloc((size_t)DIM * DIM * 2);
    _Float16* Wt2 = (_Float16*)alloc((size_t)DIM * DIM * 2);
    _Float16* gbuf = (_Float16*)alloc((size_t)MP * DIM * 2);  // g = dinv*h (f16)
    _Float16* x1f  = (_Float16*)alloc((size_t)MP * DIM * 2);  // layer-1 out / GEMM2 A
    _Float16* x2h  = (_Float16*)alloc((size_t)MP * DIM * 2);  // layer-2 out

    // --- graph norm + CSR build (parallel scan)
    k_init<<<SCAN_BLOCKS, 256, 0, stream>>>(cnt, out);
    k_count<<<(N_EDGES + 255) / 256, 256, 0, stream>>>(dst, cnt);
    k_scan_a<<<SCAN_BLOCKS, 256, 0, stream>>>(cnt, bsum);
    k_scan_b<<<1, 128, 0, stream>>>(bsum, bbase);
    k_scan_c<<<SCAN_BLOCKS, 256, 0, stream>>>(cnt, bbase, offs, cursor, dinv);
    k_fill<<<(N_EDGES + 255) / 256, 256, 0, stream>>>(src, dst, cursor, csr);

    // --- convert inputs to f16 (A padded, W transposed)
    k_cvt_feat<<<(MP * DIM / 4 + 255) / 256, 256, 0, stream>>>(features, fA);
    dim3 wgrd(16, 16, 2);
    k_cvt_w<<<wgrd, 256, 0, stream>>>(W1, W2, Wt1, Wt2);

    dim3 ggrd(MP / 128, DIM / 128);

    // --- layer 1
    k_gemm_f16<<<ggrd, 256, 0, stream>>>(fA, Wt1, dinv, gbuf);
    k_agg<<<MP / 4, 256, 0, stream>>>(gbuf, dinv, offs, csr, b1, x1f, MP);

    // --- layer 2
    k_gemm_f16<<<ggrd, 256, 0, stream>>>(x1f, Wt2, dinv, gbuf);
    k_agg<<<MP / 4, 256, 0, stream>>>(gbuf, dinv, offs, csr, b2, x2h, N_NODES);

    // --- global max pool (out zeroed in k_init)
    dim3 mgrd(2, 64);
    k_maxpool<<<mgrd, 256, 0, stream>>>(x2h, out);
}

// Round 5
// 281.776 us; speedup vs baseline: 2.4130x; 1.1356x over previous
//
#include <hip/hip_runtime.h>

#define N_NODES 20000
#define MP      20096   // N_NODES padded to multiple of 128
#define N_EDGES 320000
#define DIM     512
#define SCAN_BLOCKS 79  // ceil(20224/256), 79*256 = 20224 >= MP
#define MAXP_BLOCKS 256
#define MAXP_ROWS   79  // ceil(20000/256)

typedef _Float16 half8 __attribute__((ext_vector_type(8)));
typedef _Float16 half4v __attribute__((ext_vector_type(4)));
typedef float floatx4 __attribute__((ext_vector_type(4)));

#define GLD16(g, l) __builtin_amdgcn_global_load_lds( \
    (const __attribute__((address_space(1))) unsigned int*)(g), \
    (__attribute__((address_space(3))) unsigned int*)(l), 16, 0, 0)

// ---------------------------------------------------------------- init
// zero cnt[N_NODES] and out[DIM] in one dispatch (grid SCAN_BLOCKS x 256)
__global__ void k_init(int* __restrict__ cnt, float* __restrict__ out) {
    int i = blockIdx.x * blockDim.x + threadIdx.x;
    if (i < N_NODES) cnt[i] = 0;
    if (i < DIM) out[i] = 0.f;
}

__global__ void k_count(const int* __restrict__ dst, int* __restrict__ cnt) {
    int e = blockIdx.x * blockDim.x + threadIdx.x;
    if (e < N_EDGES) atomicAdd(&cnt[dst[e]], 1);
}

// ---------------------------------------------------------------- parallel scan
// phase A: per-block sum of 256 counts
__global__ __launch_bounds__(256) void k_scan_a(const int* __restrict__ cnt,
                                                int* __restrict__ bsum) {
    __shared__ int buf[256];
    int gi = blockIdx.x * 256 + threadIdx.x;
    buf[threadIdx.x] = (gi < N_NODES) ? cnt[gi] : 0;
    __syncthreads();
    for (int off = 128; off > 0; off >>= 1) {
        if (threadIdx.x < off) buf[threadIdx.x] += buf[threadIdx.x + off];
        __syncthreads();
    }
    if (threadIdx.x == 0) bsum[blockIdx.x] = buf[0];
}

// phase B: exclusive scan of SCAN_BLOCKS partials, single small block
__global__ __launch_bounds__(128) void k_scan_b(const int* __restrict__ bsum,
                                                int* __restrict__ bbase) {
    __shared__ int buf[128];
    int tid = threadIdx.x;
    int v = (tid < SCAN_BLOCKS) ? bsum[tid] : 0;
    buf[tid] = v;
    __syncthreads();
    for (int off = 1; off < 128; off <<= 1) {
        int t = (tid >= off) ? buf[tid - off] : 0;
        __syncthreads();
        buf[tid] += t;
        __syncthreads();
    }
    if (tid < SCAN_BLOCKS) bbase[tid] = buf[tid] - v;  // exclusive
}

// phase C: in-block inclusive scan + base -> offs, cursor, dinv (dinv padded to MP)
__global__ __launch_bounds__(256) void k_scan_c(const int* __restrict__ cnt,
                                                const int* __restrict__ bbase,
                                                int* __restrict__ offs,
                                                int* __restrict__ cursor,
                                                float* __restrict__ dinv) {
    __shared__ int buf[256];
    int tid = threadIdx.x;
    int gi = blockIdx.x * 256 + tid;
    int v = (gi < N_NODES) ? cnt[gi] : 0;
    buf[tid] = v;
    __syncthreads();
    for (int off = 1; off < 256; off <<= 1) {
        int t = (tid >= off) ? buf[tid - off] : 0;
        __syncthreads();
        buf[tid] += t;
        __syncthreads();
    }
    int base = bbase[blockIdx.x];
    if (gi < N_NODES) {
        int incl = base + buf[tid];
        offs[gi + 1] = incl;
        cursor[gi] = incl - v;
        dinv[gi] = rsqrtf((float)v + 1.0f);  // +1 self-loop
        if (gi == 0) offs[0] = 0;
    } else if (gi < MP) {
        dinv[gi] = 0.f;  // pad rows: zero (poison-proofs GEMM epilogue)
    }
}

__global__ void k_fill(const int* __restrict__ src, const int* __restrict__ dst,
                       int* __restrict__ cursor, int* __restrict__ csr_src) {
    int e = blockIdx.x * blockDim.x + threadIdx.x;
    if (e < N_EDGES) {
        int d = dst[e];
        int pos = atomicAdd(&cursor[d], 1);
        csr_src[pos] = src[e];
    }
}

// ---------------------------------------------------------------- converts
// features fp32 [N_NODES x 512] -> f16 [MP x 512], pad rows zero
__global__ __launch_bounds__(256) void k_cvt_feat(const float* __restrict__ F,
                                                  _Float16* __restrict__ A) {
    int i = blockIdx.x * blockDim.x + threadIdx.x;  // over MP*DIM/4
    int e = i * 4;
    int row = e >> 9;
    half4v o;
    if (row < N_NODES) {
        float4 v = *(const float4*)&F[e];
        o[0] = (_Float16)v.x; o[1] = (_Float16)v.y;
        o[2] = (_Float16)v.z; o[3] = (_Float16)v.w;
    } else {
        o[0] = o[1] = o[2] = o[3] = (_Float16)0.f;
    }
    *(half4v*)&A[e] = o;
}

// W fp32 [k][n] row-major -> Wt f16 [n][k] (transposed); blockIdx.z picks W1/W2
__global__ __launch_bounds__(256) void k_cvt_w(const float* __restrict__ W1,
                                               const float* __restrict__ W2,
                                               _Float16* __restrict__ Wt1,
                                               _Float16* __restrict__ Wt2) {
    const float* W = blockIdx.z ? W2 : W1;
    _Float16* Wt = blockIdx.z ? Wt2 : Wt1;
    __shared__ float tile[32][33];
    int bx = blockIdx.x * 32, by = blockIdx.y * 32;
    int x = threadIdx.x & 31, y4 = (threadIdx.x >> 5) * 4;
#pragma unroll
    for (int r = 0; r < 4; ++r)
        tile[y4 + r][x] = W[(size_t)(by + y4 + r) * DIM + bx + x];
    __syncthreads();
#pragma unroll
    for (int r = 0; r < 4; ++r)
        Wt[(size_t)(bx + y4 + r) * DIM + by + x] = (_Float16)tile[x][y4 + r];
}

// ---------------------------------------------------------------- MFMA GEMM
// g[MP,512] f16 = dinv[row] * (A[MP,512] f16 @ Bt[n][k] f16)
// 128x128 tile, BK=32, 4 waves, each wave 64x64 = 4x4 of 16x16x32 MFMA
__global__ __launch_bounds__(256) void k_gemm_f16(const _Float16* __restrict__ A,
                                                  const _Float16* __restrict__ Bt,
                                                  const float* __restrict__ dinv,
                                                  _Float16* __restrict__ G) {
    __shared__ _Float16 As[128 * 32];  // [m][k], k contiguous
    __shared__ _Float16 Bs[128 * 32];  // [n][k], k contiguous

    int t = threadIdx.x;
    int w = t >> 6, lane = t & 63;
    int lm = lane & 15, quad = lane >> 4;
    int m0 = blockIdx.x * 128, n0 = blockIdx.y * 128;
    int wm = (w & 1) * 64, wn = (w >> 1) * 64;

    floatx4 acc[4][4];
#pragma unroll
    for (int i = 0; i < 4; ++i)
#pragma unroll
        for (int j = 0; j < 4; ++j) acc[i][j] = (floatx4){0.f, 0.f, 0.f, 0.f};

    for (int k0 = 0; k0 < DIM; k0 += 32) {
        __syncthreads();  // prior-iteration LDS reads complete
#pragma unroll
        for (int i = 0; i < 2; ++i) {
            int s = i * 256 + t;          // segment id, 16B each; lane-contiguous per wave
            int m = s >> 2, kk = (s & 3) * 8;
            GLD16(A + (size_t)(m0 + m) * DIM + k0 + kk, As + s * 8);
            GLD16(Bt + (size_t)(n0 + m) * DIM + k0 + kk, Bs + s * 8);
        }
        __syncthreads();  // staging (vmcnt) drained

        half8 af[4], bf[4];
#pragma unroll
        for (int i = 0; i < 4; ++i)
            af[i] = *(const half8*)&As[(wm + i * 16 + lm) * 32 + quad * 8];
#pragma unroll
        for (int j = 0; j < 4; ++j)
            bf[j] = *(const half8*)&Bs[(wn + j * 16 + lm) * 32 + quad * 8];
#pragma unroll
        for (int i = 0; i < 4; ++i)
#pragma unroll
            for (int j = 0; j < 4; ++j)
                acc[i][j] = __builtin_amdgcn_mfma_f32_16x16x32_f16(af[i], bf[j], acc[i][j], 0, 0, 0);
    }

#pragma unroll
    for (int i = 0; i < 4; ++i)
#pragma unroll
        for (int r = 0; r < 4; ++r) {
            int row = m0 + wm + i * 16 + quad * 4 + r;
            float dd = dinv[row];  // 0 on pad rows
#pragma unroll
            for (int j = 0; j < 4; ++j) {
                int col = n0 + wn + j * 16 + lm;
                G[(size_t)row * DIM + col] = (_Float16)(dd * acc[i][j][r]);
            }
        }
}

// ---------------------------------------------------------------- aggregation
// g[s] = dinv_s * h[s] (f16). out[d] = relu( dinv_d * (g[d] + sum_e g[s]) + bias )
// One wave per node; lane covers 8 contiguous features (16 B).
// Edge loop unrolled x8 -> 8 outstanding 1KB gathers per wave.
__global__ __launch_bounds__(256) void k_agg(const _Float16* __restrict__ g,
                                             const float* __restrict__ dinv,
                                             const int* __restrict__ offs,
                                             const int* __restrict__ csr_src,
                                             const float* __restrict__ bias,
                                             _Float16* __restrict__ out, int nNodesOut) {
    int node = blockIdx.x * 4 + (threadIdx.x >> 6);
    int lane = threadIdx.x & 63;
    int f0 = lane * 8;
    if (node >= nNodesOut) return;
    if (node >= N_NODES) {  // pad row: zero (x1f feeds GEMM2's A)
        half8 z;
#pragma unroll
        for (int i = 0; i < 8; ++i) z[i] = (_Float16)0.f;
        *(half8*)&out[(size_t)node * DIM + f0] = z;
        return;
    }
    float acc[8];
    half8 self = *(const half8*)&g[(size_t)node * DIM + f0];
#pragma unroll
    for (int i = 0; i < 8; ++i) acc[i] = (float)self[i];

    int beg = offs[node], end = offs[node + 1];
    int e = beg;
    for (; e + 8 <= end; e += 8) {
        int s0 = csr_src[e],     s1 = csr_src[e + 1], s2 = csr_src[e + 2], s3 = csr_src[e + 3];
        int s4 = csr_src[e + 4], s5 = csr_src[e + 5], s6 = csr_src[e + 6], s7 = csr_src[e + 7];
        half8 v0 = *(const half8*)&g[(size_t)s0 * DIM + f0];
        half8 v1 = *(const half8*)&g[(size_t)s1 * DIM + f0];
        half8 v2 = *(const half8*)&g[(size_t)s2 * DIM + f0];
        half8 v3 = *(const half8*)&g[(size_t)s3 * DIM + f0];
        half8 v4 = *(const half8*)&g[(size_t)s4 * DIM + f0];
        half8 v5 = *(const half8*)&g[(size_t)s5 * DIM + f0];
        half8 v6 = *(const half8*)&g[(size_t)s6 * DIM + f0];
        half8 v7 = *(const half8*)&g[(size_t)s7 * DIM + f0];
#pragma unroll
        for (int i = 0; i < 8; ++i)
            acc[i] += ((float)v0[i] + (float)v1[i]) + ((float)v2[i] + (float)v3[i]) +
                      ((float)v4[i] + (float)v5[i]) + ((float)v6[i] + (float)v7[i]);
    }
    for (; e + 4 <= end; e += 4) {
        int s0 = csr_src[e], s1 = csr_src[e + 1], s2 = csr_src[e + 2], s3 = csr_src[e + 3];
        half8 v0 = *(const half8*)&g[(size_t)s0 * DIM + f0];
        half8 v1 = *(const half8*)&g[(size_t)s1 * DIM + f0];
        half8 v2 = *(const half8*)&g[(size_t)s2 * DIM + f0];
        half8 v3 = *(const half8*)&g[(size_t)s3 * DIM + f0];
#pragma unroll
        for (int i = 0; i < 8; ++i)
            acc[i] += ((float)v0[i] + (float)v1[i]) + ((float)v2[i] + (float)v3[i]);
    }
    for (; e < end; ++e) {
        int s = csr_src[e];
        half8 v = *(const half8*)&g[(size_t)s * DIM + f0];
#pragma unroll
        for (int i = 0; i < 8; ++i) acc[i] += (float)v[i];
    }
    float dd = dinv[node];
    float4 b0 = *(const float4*)&bias[f0];
    float4 b1 = *(const float4*)&bias[f0 + 4];
    float bb[8] = {b0.x, b0.y, b0.z, b0.w, b1.x, b1.y, b1.z, b1.w};
    half8 o;
#pragma unroll
    for (int i = 0; i < 8; ++i) o[i] = (_Float16)fmaxf(fmaf(dd, acc[i], bb[i]), 0.f);
    *(half8*)&out[(size_t)node * DIM + f0] = o;
}

// ---------------------------------------------------------------- max pool
// 256 blocks; 4 row-streams/block; each wave streams whole 1KB rows (lane=half8).
// LDS-combine the 4 streams, one atomicMax per feature per block.
// Values are post-ReLU (>=0) so int-compare == float-compare; out zeroed in k_init.
__global__ __launch_bounds__(256) void k_maxpool(const _Float16* __restrict__ x,
                                                 float* __restrict__ out) {
    __shared__ float lmax[4][DIM];
    int stream = threadIdx.x >> 6, lane = threadIdx.x & 63;
    int f0 = lane * 8;
    int r0 = blockIdx.x * MAXP_ROWS;
    int r1 = min(r0 + MAXP_ROWS, N_NODES);

    float m[8];
#pragma unroll
    for (int i = 0; i < 8; ++i) m[i] = 0.f;
    for (int r = r0 + stream; r < r1; r += 4) {
        half8 v = *(const half8*)&x[(size_t)r * DIM + f0];
#pragma unroll
        for (int i = 0; i < 8; ++i) m[i] = fmaxf(m[i], (float)v[i]);
    }
#pragma unroll
    for (int i = 0; i < 8; ++i) lmax[stream][f0 + i] = m[i];
    __syncthreads();
    // 256 threads x 2 features: combine 4 streams, one atomic each
#pragma unroll
    for (int rep = 0; rep < 2; ++rep) {
        int f = rep * 256 + threadIdx.x;
        float v = fmaxf(fmaxf(lmax[0][f], lmax[1][f]), fmaxf(lmax[2][f], lmax[3][f]));
        atomicMax((int*)&out[f], __float_as_int(v));
    }
}

// ---------------------------------------------------------------- launch
extern "C" void kernel_launch(void* const* d_in, const int* in_sizes, int n_in,
                              void* d_out, int out_size, void* d_ws, size_t ws_size,
                              hipStream_t stream) {
    const float* features = (const float*)d_in[0];
    const int*   ei       = (const int*)d_in[1];
    const float* W1       = (const float*)d_in[3];
    const float* b1       = (const float*)d_in[4];
    const float* W2       = (const float*)d_in[5];
    const float* b2       = (const float*)d_in[6];
    float* out = (float*)d_out;

    const int* src = ei;
    const int* dst = ei + N_EDGES;

    // workspace carve-up
    char* p = (char*)d_ws;
    auto alloc = [&](size_t bytes) { void* r = p; p += (bytes + 255) & ~(size_t)255; return r; };
    int*      cnt    = (int*)alloc(N_NODES * 4);
    int*      offs   = (int*)alloc((N_NODES + 1) * 4);
    int*      cursor = (int*)alloc(N_NODES * 4);
    float*    dinv   = (float*)alloc(MP * 4);
    int*      csr    = (int*)alloc(N_EDGES * 4);
    int*      bsum   = (int*)alloc(SCAN_BLOCKS * 4);
    int*      bbase  = (int*)alloc(SCAN_BLOCKS * 4);
    _Float16* fA  = (_Float16*)alloc((size_t)MP * DIM * 2);   // GEMM1 A
    _Float16* Wt1 = (_Float16*)alloc((size_t)DIM * DIM * 2);
    _Float16* Wt2 = (_Float16*)alloc((size_t)DIM * DIM * 2);
    _Float16* gbuf = (_Float16*)alloc((size_t)MP * DIM * 2);  // g = dinv*h (f16)
    _Float16* x1f  = (_Float16*)alloc((size_t)MP * DIM * 2);  // layer-1 out / GEMM2 A
    _Float16* x2h  = (_Float16*)alloc((size_t)MP * DIM * 2);  // layer-2 out

    // --- graph norm + CSR build (parallel scan)
    k_init<<<SCAN_BLOCKS, 256, 0, stream>>>(cnt, out);
    k_count<<<(N_EDGES + 255) / 256, 256, 0, stream>>>(dst, cnt);
    k_scan_a<<<SCAN_BLOCKS, 256, 0, stream>>>(cnt, bsum);
    k_scan_b<<<1, 128, 0, stream>>>(bsum, bbase);
    k_scan_c<<<SCAN_BLOCKS, 256, 0, stream>>>(cnt, bbase, offs, cursor, dinv);
    k_fill<<<(N_EDGES + 255) / 256, 256, 0, stream>>>(src, dst, cursor, csr);

    // --- convert inputs to f16 (A padded, W transposed)
    k_cvt_feat<<<(MP * DIM / 4 + 255) / 256, 256, 0, stream>>>(features, fA);
    dim3 wgrd(16, 16, 2);
    k_cvt_w<<<wgrd, 256, 0, stream>>>(W1, W2, Wt1, Wt2);

    dim3 ggrd(MP / 128, DIM / 128);

    // --- layer 1
    k_gemm_f16<<<ggrd, 256, 0, stream>>>(fA, Wt1, dinv, gbuf);
    k_agg<<<MP / 4, 256, 0, stream>>>(gbuf, dinv, offs, csr, b1, x1f, MP);

    // --- layer 2
    k_gemm_f16<<<ggrd, 256, 0, stream>>>(x1f, Wt2, dinv, gbuf);
    k_agg<<<MP / 4, 256, 0, stream>>>(gbuf, dinv, offs, csr, b2, x2h, N_NODES);

    // --- global max pool (out zeroed in k_init)
    k_maxpool<<<MAXP_BLOCKS, 256, 0, stream>>>(x2h, out);
}

// Round 6
// 281.403 us; speedup vs baseline: 2.4162x; 1.0013x over previous
//
#include <hip/hip_runtime.h>

#define N_NODES 20000
#define MP      20096   // N_NODES padded to multiple of 128
#define N_EDGES 320000
#define DIM     512
#define SCAN_BLOCKS 79   // ceil(20224/256)
#define FILL_BLOCKS 1250 // N_EDGES/256
#define CVT_BLOCKS  10048 // MP*DIM/4/256
#define W_BLOCKS    512   // 16x16 tiles x 2 weights
#define MAXP_BLOCKS 256
#define MAXP_ROWS   79   // ceil(20000/256)

typedef _Float16 half8 __attribute__((ext_vector_type(8)));
typedef _Float16 half4v __attribute__((ext_vector_type(4)));
typedef _Float16 half2v __attribute__((ext_vector_type(2)));
typedef float floatx4 __attribute__((ext_vector_type(4)));

#define GLD16(g, l) __builtin_amdgcn_global_load_lds( \
    (const __attribute__((address_space(1))) unsigned int*)(g), \
    (__attribute__((address_space(3))) unsigned int*)(l), 16, 0, 0)

__global__ void k_count(const int* __restrict__ dst, int* __restrict__ cnt) {
    int e = blockIdx.x * blockDim.x + threadIdx.x;
    if (e < N_EDGES) atomicAdd(&cnt[dst[e]], 1);
}

// ---------------------------------------------------------------- parallel scan
__global__ __launch_bounds__(256) void k_scan_a(const int* __restrict__ cnt,
                                                int* __restrict__ bsum) {
    __shared__ int buf[256];
    int gi = blockIdx.x * 256 + threadIdx.x;
    buf[threadIdx.x] = (gi < N_NODES) ? cnt[gi] : 0;
    __syncthreads();
    for (int off = 128; off > 0; off >>= 1) {
        if (threadIdx.x < off) buf[threadIdx.x] += buf[threadIdx.x + off];
        __syncthreads();
    }
    if (threadIdx.x == 0) bsum[blockIdx.x] = buf[0];
}

__global__ __launch_bounds__(128) void k_scan_b(const int* __restrict__ bsum,
                                                int* __restrict__ bbase) {
    __shared__ int buf[128];
    int tid = threadIdx.x;
    int v = (tid < SCAN_BLOCKS) ? bsum[tid] : 0;
    buf[tid] = v;
    __syncthreads();
    for (int off = 1; off < 128; off <<= 1) {
        int t = (tid >= off) ? buf[tid - off] : 0;
        __syncthreads();
        buf[tid] += t;
        __syncthreads();
    }
    if (tid < SCAN_BLOCKS) bbase[tid] = buf[tid] - v;  // exclusive
}

__global__ __launch_bounds__(256) void k_scan_c(const int* __restrict__ cnt,
                                                const int* __restrict__ bbase,
                                                int* __restrict__ offs,
                                                int* __restrict__ cursor,
                                                float* __restrict__ dinv) {
    __shared__ int buf[256];
    int tid = threadIdx.x;
    int gi = blockIdx.x * 256 + tid;
    int v = (gi < N_NODES) ? cnt[gi] : 0;
    buf[tid] = v;
    __syncthreads();
    for (int off = 1; off < 256; off <<= 1) {
        int t = (tid >= off) ? buf[tid - off] : 0;
        __syncthreads();
        buf[tid] += t;
        __syncthreads();
    }
    int base = bbase[blockIdx.x];
    if (gi < N_NODES) {
        int incl = base + buf[tid];
        offs[gi + 1] = incl;
        cursor[gi] = incl - v;
        dinv[gi] = rsqrtf((float)v + 1.0f);  // +1 self-loop
        if (gi == 0) offs[0] = 0;
    } else if (gi < MP) {
        dinv[gi] = 0.f;  // pad rows: zero (poison-proofs GEMM epilogue)
    }
}

// ---------------------------------------------------------------- fused prep
// blocks [0,1250): CSR fill; [1250,11298): feature cvt; [11298,11810): W transpose
__global__ __launch_bounds__(256) void k_prep(const int* __restrict__ src,
                                              const int* __restrict__ dst,
                                              int* __restrict__ cursor,
                                              int* __restrict__ csr_src,
                                              const float* __restrict__ F,
                                              _Float16* __restrict__ A,
                                              const float* __restrict__ W1,
                                              const float* __restrict__ W2,
                                              _Float16* __restrict__ Wt1,
                                              _Float16* __restrict__ Wt2) {
    int b = blockIdx.x;
    if (b < FILL_BLOCKS) {
        int e = b * 256 + threadIdx.x;
        int d = dst[e];
        int pos = atomicAdd(&cursor[d], 1);
        csr_src[pos] = src[e];
        return;
    }
    if (b < FILL_BLOCKS + CVT_BLOCKS) {
        int i = (b - FILL_BLOCKS) * 256 + threadIdx.x;  // over MP*DIM/4
        int e = i * 4;
        int row = e >> 9;
        half4v o;
        if (row < N_NODES) {
            float4 v = *(const float4*)&F[e];
            o[0] = (_Float16)v.x; o[1] = (_Float16)v.y;
            o[2] = (_Float16)v.z; o[3] = (_Float16)v.w;
        } else {
            o[0] = o[1] = o[2] = o[3] = (_Float16)0.f;
        }
        *(half4v*)&A[e] = o;
        return;
    }
    // W transpose: fp32 [k][n] -> f16 [n][k]
    int local = b - (FILL_BLOCKS + CVT_BLOCKS);
    int z = local >> 8, t = local & 255;
    const float* W = z ? W2 : W1;
    _Float16* Wt = z ? Wt2 : Wt1;
    __shared__ float tile[32][33];
    int bx = (t & 15) * 32, by = (t >> 4) * 32;
    int x = threadIdx.x & 31, y4 = (threadIdx.x >> 5) * 4;
#pragma unroll
    for (int r = 0; r < 4; ++r)
        tile[y4 + r][x] = W[(size_t)(by + y4 + r) * DIM + bx + x];
    __syncthreads();
#pragma unroll
    for (int r = 0; r < 4; ++r)
        Wt[(size_t)(bx + y4 + r) * DIM + by + x] = (_Float16)tile[x][y4 + r];
}

// ---------------------------------------------------------------- MFMA GEMM
// g[MP,512] f16 = dinv[row] * (A[MP,512] f16 @ Bt[n][k] f16)
__global__ __launch_bounds__(256) void k_gemm_f16(const _Float16* __restrict__ A,
                                                  const _Float16* __restrict__ Bt,
                                                  const float* __restrict__ dinv,
                                                  _Float16* __restrict__ G) {
    __shared__ _Float16 As[128 * 32];  // [m][k], k contiguous
    __shared__ _Float16 Bs[128 * 32];  // [n][k], k contiguous

    int t = threadIdx.x;
    int w = t >> 6, lane = t & 63;
    int lm = lane & 15, quad = lane >> 4;
    int m0 = blockIdx.x * 128, n0 = blockIdx.y * 128;
    int wm = (w & 1) * 64, wn = (w >> 1) * 64;

    floatx4 acc[4][4];
#pragma unroll
    for (int i = 0; i < 4; ++i)
#pragma unroll
        for (int j = 0; j < 4; ++j) acc[i][j] = (floatx4){0.f, 0.f, 0.f, 0.f};

    for (int k0 = 0; k0 < DIM; k0 += 32) {
        __syncthreads();
#pragma unroll
        for (int i = 0; i < 2; ++i) {
            int s = i * 256 + t;
            int m = s >> 2, kk = (s & 3) * 8;
            GLD16(A + (size_t)(m0 + m) * DIM + k0 + kk, As + s * 8);
            GLD16(Bt + (size_t)(n0 + m) * DIM + k0 + kk, Bs + s * 8);
        }
        __syncthreads();

        half8 af[4], bf[4];
#pragma unroll
        for (int i = 0; i < 4; ++i)
            af[i] = *(const half8*)&As[(wm + i * 16 + lm) * 32 + quad * 8];
#pragma unroll
        for (int j = 0; j < 4; ++j)
            bf[j] = *(const half8*)&Bs[(wn + j * 16 + lm) * 32 + quad * 8];
#pragma unroll
        for (int i = 0; i < 4; ++i)
#pragma unroll
            for (int j = 0; j < 4; ++j)
                acc[i][j] = __builtin_amdgcn_mfma_f32_16x16x32_f16(af[i], bf[j], acc[i][j], 0, 0, 0);
    }

#pragma unroll
    for (int i = 0; i < 4; ++i)
#pragma unroll
        for (int r = 0; r < 4; ++r) {
            int row = m0 + wm + i * 16 + quad * 4 + r;
            float dd = dinv[row];  // 0 on pad rows
#pragma unroll
            for (int j = 0; j < 4; ++j) {
                int col = n0 + wn + j * 16 + lm;
                G[(size_t)row * DIM + col] = (_Float16)(dd * acc[i][j][r]);
            }
        }
}

// ---------------------------------------------------------------- aggregation
// Block = 1 node; 4 waves split the edge list round-robin; LDS-combine.
// out[d] = relu( dinv_d * (g[d] + sum_e g[s]) + bias ),  g[s] = dinv_s*h[s] (f16)
__global__ __launch_bounds__(256) void k_agg(const _Float16* __restrict__ g,
                                             const float* __restrict__ dinv,
                                             const int* __restrict__ offs,
                                             const int* __restrict__ csr_src,
                                             const float* __restrict__ bias,
                                             _Float16* __restrict__ out) {
    int node = blockIdx.x;
    if (node >= N_NODES) {  // pad row: zero (x1f feeds GEMM2's A)
        ((unsigned int*)&out[(size_t)node * DIM])[threadIdx.x] = 0u;
        return;
    }
    __shared__ float part[4][DIM];
    int w = threadIdx.x >> 6, lane = threadIdx.x & 63;
    int f0 = lane * 8;

    float acc[8];
    if (w == 0) {
        half8 self = *(const half8*)&g[(size_t)node * DIM + f0];
#pragma unroll
        for (int i = 0; i < 8; ++i) acc[i] = (float)self[i];
    } else {
#pragma unroll
        for (int i = 0; i < 8; ++i) acc[i] = 0.f;
    }

    int beg = offs[node], end = offs[node + 1];
    int e = beg + w;  // wave w takes edges beg+w, +4, +8, ... (round-robin)
    for (; e + 12 < end; e += 16) {
        int s0 = csr_src[e], s1 = csr_src[e + 4], s2 = csr_src[e + 8], s3 = csr_src[e + 12];
        half8 v0 = *(const half8*)&g[(size_t)s0 * DIM + f0];
        half8 v1 = *(const half8*)&g[(size_t)s1 * DIM + f0];
        half8 v2 = *(const half8*)&g[(size_t)s2 * DIM + f0];
        half8 v3 = *(const half8*)&g[(size_t)s3 * DIM + f0];
#pragma unroll
        for (int i = 0; i < 8; ++i)
            acc[i] += ((float)v0[i] + (float)v1[i]) + ((float)v2[i] + (float)v3[i]);
    }
    for (; e < end; e += 4) {
        int s = csr_src[e];
        half8 v = *(const half8*)&g[(size_t)s * DIM + f0];
#pragma unroll
        for (int i = 0; i < 8; ++i) acc[i] += (float)v[i];
    }
#pragma unroll
    for (int i = 0; i < 8; ++i) part[w][f0 + i] = acc[i];
    __syncthreads();

    // 256 threads x 2 consecutive features: combine 4 partials, write packed f16
    int f = threadIdx.x * 2;
    float dd = dinv[node];
    float s0 = part[0][f] + part[1][f] + part[2][f] + part[3][f];
    float s1 = part[0][f + 1] + part[1][f + 1] + part[2][f + 1] + part[3][f + 1];
    half2v o;
    o[0] = (_Float16)fmaxf(fmaf(dd, s0, bias[f]), 0.f);
    o[1] = (_Float16)fmaxf(fmaf(dd, s1, bias[f + 1]), 0.f);
    *(half2v*)&out[(size_t)node * DIM + f] = o;
}

// ---------------------------------------------------------------- max pool
__global__ __launch_bounds__(256) void k_maxpool(const _Float16* __restrict__ x,
                                                 float* __restrict__ out) {
    __shared__ float lmax[4][DIM];
    int stream = threadIdx.x >> 6, lane = threadIdx.x & 63;
    int f0 = lane * 8;
    int r0 = blockIdx.x * MAXP_ROWS;
    int r1 = min(r0 + MAXP_ROWS, N_NODES);

    float m[8];
#pragma unroll
    for (int i = 0; i < 8; ++i) m[i] = 0.f;
    for (int r = r0 + stream; r < r1; r += 4) {
        half8 v = *(const half8*)&x[(size_t)r * DIM + f0];
#pragma unroll
        for (int i = 0; i < 8; ++i) m[i] = fmaxf(m[i], (float)v[i]);
    }
#pragma unroll
    for (int i = 0; i < 8; ++i) lmax[stream][f0 + i] = m[i];
    __syncthreads();
#pragma unroll
    for (int rep = 0; rep < 2; ++rep) {
        int f = rep * 256 + threadIdx.x;
        float v = fmaxf(fmaxf(lmax[0][f], lmax[1][f]), fmaxf(lmax[2][f], lmax[3][f]));
        atomicMax((int*)&out[f], __float_as_int(v));  // post-ReLU >= 0: int cmp == float cmp
    }
}

// ---------------------------------------------------------------- launch
extern "C" void kernel_launch(void* const* d_in, const int* in_sizes, int n_in,
                              void* d_out, int out_size, void* d_ws, size_t ws_size,
                              hipStream_t stream) {
    const float* features = (const float*)d_in[0];
    const int*   ei       = (const int*)d_in[1];
    const float* W1       = (const float*)d_in[3];
    const float* b1       = (const float*)d_in[4];
    const float* W2       = (const float*)d_in[5];
    const float* b2       = (const float*)d_in[6];
    float* out = (float*)d_out;

    const int* src = ei;
    const int* dst = ei + N_EDGES;

    char* p = (char*)d_ws;
    auto alloc = [&](size_t bytes) { void* r = p; p += (bytes + 255) & ~(size_t)255; return r; };
    int*      cnt    = (int*)alloc(N_NODES * 4);
    int*      offs   = (int*)alloc((N_NODES + 1) * 4);
    int*      cursor = (int*)alloc(N_NODES * 4);
    float*    dinv   = (float*)alloc(MP * 4);
    int*      csr    = (int*)alloc(N_EDGES * 4);
    int*      bsum   = (int*)alloc(SCAN_BLOCKS * 4);
    int*      bbase  = (int*)alloc(SCAN_BLOCKS * 4);
    _Float16* fA   = (_Float16*)alloc((size_t)MP * DIM * 2);
    _Float16* Wt1  = (_Float16*)alloc((size_t)DIM * DIM * 2);
    _Float16* Wt2  = (_Float16*)alloc((size_t)DIM * DIM * 2);
    _Float16* gbuf = (_Float16*)alloc((size_t)MP * DIM * 2);
    _Float16* x1f  = (_Float16*)alloc((size_t)MP * DIM * 2);
    _Float16* x2h  = (_Float16*)alloc((size_t)MP * DIM * 2);

    // --- zero cnt + out (memset nodes are cheaper than a kernel dispatch)
    hipMemsetAsync(cnt, 0, N_NODES * 4, stream);
    hipMemsetAsync(out, 0, DIM * 4, stream);

    // --- graph norm + CSR build
    k_count<<<FILL_BLOCKS, 256, 0, stream>>>(dst, cnt);
    k_scan_a<<<SCAN_BLOCKS, 256, 0, stream>>>(cnt, bsum);
    k_scan_b<<<1, 128, 0, stream>>>(bsum, bbase);
    k_scan_c<<<SCAN_BLOCKS, 256, 0, stream>>>(cnt, bbase, offs, cursor, dinv);

    // --- fused: CSR fill + feature f16 cvt + W transposes
    k_prep<<<FILL_BLOCKS + CVT_BLOCKS + W_BLOCKS, 256, 0, stream>>>(
        src, dst, cursor, csr, features, fA, W1, W2, Wt1, Wt2);

    dim3 ggrd(MP / 128, DIM / 128);

    // --- layer 1
    k_gemm_f16<<<ggrd, 256, 0, stream>>>(fA, Wt1, dinv, gbuf);
    k_agg<<<MP, 256, 0, stream>>>(gbuf, dinv, offs, csr, b1, x1f);

    // --- layer 2
    k_gemm_f16<<<ggrd, 256, 0, stream>>>(x1f, Wt2, dinv, gbuf);
    k_agg<<<N_NODES, 256, 0, stream>>>(gbuf, dinv, offs, csr, b2, x2h);

    // --- global max pool (out zeroed by memset)
    k_maxpool<<<MAXP_BLOCKS, 256, 0, stream>>>(x2h, out);
}